// Round 7
// baseline (8626.631 us; speedup 1.0000x reference)
//
#include <hip/hip_runtime.h>

// FPS: x (B=64, N=65536, 3) f32 -> out (B, M=2048, 3) f32 gathered points.
// Verified fp semantics (round 3, absmax=0):
//   d = fma(dz,dz, round(dx*dx) + round(dy*dy)), min via fminf,
//   argmax tie-break = smallest global index.
// Round-7 (protocol identical to r6; scheduling/residency fixes):
//  - "+a" pins: coords constrained into AGPRs (gfx950 unified file) ->
//    zero-cost residency (r6's "+v" pins forced VGPR materialization and
//    the compiler shuttled via v_accvgpr_read/write every iteration)
//  - s_setprio(1) around wave0's exchange (critical path vs spinning waves)
//  - s_sleep(1) in non-wave0 broadcast-spin misses (issue-slot relief;
//    VALUBusy was 78% of pure spin/shuttle issue)

#define FPS_B 64
#define FPS_N 65536
#define FPS_M 2048
#define FPS_T 1024
#define FPS_Q 4                    // blocks per batch
#define FPS_GT (FPS_T * FPS_Q)     // 4096 threads per batch
#define FPS_PPT (FPS_N / FPS_GT)   // 16 points per thread
#define FPS_WAVES (FPS_T / 64)     // 16 waves per block

#define SLOT_U64 8                 // 64B global slot
#define BATCH_U64 (FPS_Q * 2 * SLOT_U64)

#define AG_LOAD(p)    __hip_atomic_load((p), __ATOMIC_RELAXED, __HIP_MEMORY_SCOPE_AGENT)
#define AG_STORE(p,v) __hip_atomic_store((p), (v), __ATOMIC_RELAXED, __HIP_MEMORY_SCOPE_AGENT)
#define WG_LOAD(p)    __hip_atomic_load((p), __ATOMIC_RELAXED, __HIP_MEMORY_SCOPE_WORKGROUP)
#define WG_STORE(p,v) __hip_atomic_store((p), (v), __ATOMIC_RELAXED, __HIP_MEMORY_SCOPE_WORKGROUP)

// AGPR pin: allocation-only (empty asm), keeps values in the unified
// register file across the loop without remat-by-reload being legal.
#define PIN4(a,b,c,d) asm volatile("" : "+a"(a), "+a"(b), "+a"(c), "+a"(d))

__global__ __launch_bounds__(FPS_T, 4)
void fps_kernel(const float* __restrict__ x, float* __restrict__ out,
                unsigned long long* __restrict__ cand) {
    const int bid = blockIdx.x;
    // XCD-affine swizzle: batch b's 4 blocks share bid%8 (same XCD under
    // round-robin dispatch). Bijective over [0,256).
    const int c = bid & 7;
    const int v = bid >> 3;
    const int q = v & 3;           // block-in-batch
    const int b = (v >> 2) * 8 + c;

    const float* xb = x + (size_t)b * FPS_N * 3;
    float* ob = out + (size_t)b * FPS_M * 3;
    unsigned long long* cb = cand + (size_t)b * BATCH_U64;

    // stamped LDS mailboxes: 16 wave entries x 4 words, 3 broadcast words
    __shared__ unsigned long long s_entry[FPS_WAVES * 4];
    __shared__ unsigned long long s_bcast[3];

    const int t = threadIdx.x;
    const int wave = t >> 6;
    const int lane = t & 63;
    const int g = q * FPS_T + t;   // 0..4095 within batch

    if (t < FPS_WAVES * 4) WG_STORE(&s_entry[t], 0ull);
    if (t >= 64 && t < 67)  WG_STORE(&s_bcast[t - 64], 0ull);
    __syncthreads();               // the only barrier in the kernel

    // one-time coordinate load; point i = k*4096 + g (ascending in k)
    float cx0,cx1,cx2,cx3,cx4,cx5,cx6,cx7,cx8,cx9,cx10,cx11,cx12,cx13,cx14,cx15;
    float cy0,cy1,cy2,cy3,cy4,cy5,cy6,cy7,cy8,cy9,cy10,cy11,cy12,cy13,cy14,cy15;
    float cz0,cz1,cz2,cz3,cz4,cz5,cz6,cz7,cz8,cz9,cz10,cz11,cz12,cz13,cz14,cz15;
    float mind[FPS_PPT];
#define LOADK(k) do { const int i = (k) * FPS_GT + g; \
        cx##k = xb[3*i+0]; cy##k = xb[3*i+1]; cz##k = xb[3*i+2]; \
        mind[k] = INFINITY; } while (0)
    LOADK(0); LOADK(1); LOADK(2); LOADK(3); LOADK(4); LOADK(5); LOADK(6); LOADK(7);
    LOADK(8); LOADK(9); LOADK(10); LOADK(11); LOADK(12); LOADK(13); LOADK(14); LOADK(15);
#undef LOADK

    float px = xb[0], py = xb[1], pz = xb[2];
    if (q == 0 && t == 0) { ob[0] = px; ob[1] = py; ob[2] = pz; }

    long long budget = 1LL << 22;  // fail-safe: degrade, don't hang

    for (int s = 1; s < FPS_M; ++s) {
        // keep the 48 coord values resident (AGPR-constrained, zero moves)
        PIN4(cx0,cx1,cx2,cx3);   PIN4(cx4,cx5,cx6,cx7);
        PIN4(cx8,cx9,cx10,cx11); PIN4(cx12,cx13,cx14,cx15);
        PIN4(cy0,cy1,cy2,cy3);   PIN4(cy4,cy5,cy6,cy7);
        PIN4(cy8,cy9,cy10,cy11); PIN4(cy12,cy13,cy14,cy15);
        PIN4(cz0,cz1,cz2,cz3);   PIN4(cz4,cz5,cz6,cz7);
        PIN4(cz8,cz9,cz10,cz11); PIN4(cz12,cz13,cz14,cz15);

        float best = -INFINITY;
        int besti = 0;
        float bx = 0.f, by = 0.f, bz = 0.f;
#define STEPK(k) do { \
        const float dx = __fsub_rn(cx##k, px); \
        const float dy = __fsub_rn(cy##k, py); \
        const float dz = __fsub_rn(cz##k, pz); \
        const float sxy = __fadd_rn(__fmul_rn(dx, dx), __fmul_rn(dy, dy)); \
        const float d = __builtin_fmaf(dz, dz, sxy); \
        const float md = fminf(mind[k], d); \
        mind[k] = md; \
        if (md > best) { best = md; besti = (k) * FPS_GT + g; \
                         bx = cx##k; by = cy##k; bz = cz##k; } } while (0)
        STEPK(0); STEPK(1); STEPK(2); STEPK(3); STEPK(4); STEPK(5); STEPK(6); STEPK(7);
        STEPK(8); STEPK(9); STEPK(10); STEPK(11); STEPK(12); STEPK(13); STEPK(14); STEPK(15);
#undef STEPK

        // wave argmax on (val, idx), smallest-index tie-break
#pragma unroll
        for (int m = 32; m >= 1; m >>= 1) {
            const float ov = __shfl_xor(best, m);
            const int   oi = __shfl_xor(besti, m);
            if (ov > best || (ov == best && oi < besti)) { best = ov; besti = oi; }
        }
        // winner lane = besti & 63 (i = k*4096 + q*1024 + t; 4096,1024 ≡ 0 mod 64)
        const int wl = besti & 63;
        const float wx = __shfl(bx, wl);
        const float wy = __shfl(by, wl);
        const float wz = __shfl(bz, wl);

        const unsigned long long want = (unsigned long long)s;
        const int ring = s & 1;

        // wave leaders publish stamped entry (lanes 0-3, one store instr)
        if (lane < 4) {
            unsigned long long w;
            if (lane == 0)
                w = ((unsigned long long)__float_as_uint(best) << 32) |
                    ((unsigned long long)((~(unsigned)besti) & 0xFFFFu) << 11) | want;
            else if (lane == 1) w = ((unsigned long long)__float_as_uint(wx) << 32) | want;
            else if (lane == 2) w = ((unsigned long long)__float_as_uint(wy) << 32) | want;
            else                w = ((unsigned long long)__float_as_uint(wz) << 32) | want;
            WG_STORE(&s_entry[wave * 4 + lane], w);
        }

        if (wave == 0) {
            __builtin_amdgcn_s_setprio(1);   // critical path: suppress spinners
            // gather 16 entries (lanes mirror mod 16), stamped spin
            const int e = lane & 15;
            unsigned long long e0;
            do { e0 = WG_LOAD(&s_entry[e * 4]); } while ((e0 & 0x7FFull) != want && --budget > 0);
            // butterfly within 16-lane groups
#pragma unroll
            for (int m = 8; m >= 1; m >>= 1) {
                const unsigned long long o = __shfl_xor(e0, m);
                if (o > e0) e0 = o;
            }
            // winner wave in this block: idx&1023 = t, wave = t>>6
            const int widx = (int)((~(unsigned)(e0 >> 11)) & 0xFFFFu);
            const int wv = (widx & 1023) >> 6;
            unsigned long long cw = 0;
            if (lane >= 1 && lane <= 3) {
                do { cw = WG_LOAD(&s_entry[wv * 4 + lane]); } while ((cw & 0x7FFull) != want && --budget > 0);
            }
            // publish block winner to global slot (lanes 0-3, one store instr)
            if (lane < 4) {
                const unsigned long long pw = (lane == 0) ? e0 : cw;
                AG_STORE(&cb[(q * 2 + ring) * SLOT_U64 + lane], pw);
            }
            // poll all 4 slots' w0 (lane l <-> slot l), stamped spin
            unsigned long long pv = 0;
            if (lane < 4) {
                do { pv = AG_LOAD(&cb[(lane * 2 + ring) * SLOT_U64]); } while ((pv & 0x7FFull) != want && --budget > 0);
            }
            // combine across lanes 0-3
            {
                const unsigned long long o1 = __shfl_xor(pv, 1);
                if (o1 > pv) pv = o1;
                const unsigned long long o2 = __shfl_xor(pv, 2);
                if (o2 > pv) pv = o2;
            }
            // winner block from idx: g = idx&4095, q_win = g>>10
            const int widx2 = (int)((~(unsigned)(pv >> 11)) & 0xFFFFu);
            const int wb = (widx2 & 4095) >> 10;
            unsigned long long cw2 = 0;
            if (lane >= 1 && lane <= 3) {
                do { cw2 = AG_LOAD(&cb[(wb * 2 + ring) * SLOT_U64 + lane]); } while ((cw2 & 0x7FFull) != want && --budget > 0);
                WG_STORE(&s_bcast[lane - 1], cw2);
            }
            __builtin_amdgcn_s_setprio(0);
        }

        // all waves: stamped spin on broadcast coords (non-critical waves
        // sleep per miss to free issue slots for wave0's exchange)
        unsigned long long b0, b1, b2;
        if (wave != 0) {
            for (;;) {
                b0 = WG_LOAD(&s_bcast[0]);
                if ((b0 & 0x7FFull) == want || --budget <= 0) break;
                __builtin_amdgcn_s_sleep(1);
            }
        } else {
            do { b0 = WG_LOAD(&s_bcast[0]); } while ((b0 & 0x7FFull) != want && --budget > 0);
        }
        do { b1 = WG_LOAD(&s_bcast[1]); } while ((b1 & 0x7FFull) != want && --budget > 0);
        do { b2 = WG_LOAD(&s_bcast[2]); } while ((b2 & 0x7FFull) != want && --budget > 0);
        px = __uint_as_float((unsigned)(b0 >> 32));
        py = __uint_as_float((unsigned)(b1 >> 32));
        pz = __uint_as_float((unsigned)(b2 >> 32));

        if (q == 0 && t == 0) {
            ob[3 * s + 0] = px; ob[3 * s + 1] = py; ob[3 * s + 2] = pz;
        }
    }
}

extern "C" void kernel_launch(void* const* d_in, const int* in_sizes, int n_in,
                              void* d_out, int out_size, void* d_ws, size_t ws_size,
                              hipStream_t stream) {
    const float* x = (const float*)d_in[0];
    float* out = (float*)d_out;
    unsigned long long* cand = (unsigned long long*)d_ws;
    (void)in_sizes; (void)n_in; (void)out_size; (void)ws_size;
    // zero sync workspace each launch (stale stamps can't match: seq >= 1)
    hipMemsetAsync(d_ws, 0, FPS_B * BATCH_U64 * sizeof(unsigned long long), stream);
    fps_kernel<<<FPS_B * FPS_Q, FPS_T, 0, stream>>>(x, out, cand);
}

// Round 8
// 7334.534 us; speedup vs baseline: 1.1762x; 1.1762x over previous
//
#include <hip/hip_runtime.h>

// FPS: x (B=64, N=65536, 3) f32 -> out (B, M=2048, 3) f32 gathered points.
// Verified fp semantics (round 3, absmax=0):
//   d = fma(dz,dz, round(dx*dx) + round(dy*dy)), min via fminf,
//   argmax tie-break = smallest global index.
// Round-8:
//  - intra-block sync via 2x s_barrier (waves park, zero spin issue;
//    r6/r7 had 75-78% VALUBusy of pure spin pollution)
//  - single-load intra-block gather: s_entry[lane] (64 u64 = 16 waves x 4
//    words), butterfly over word-0 coset
//  - merged global poll: wave0's 64 lanes poll all 4 slots x 4 words in one
//    load/round; winner AND coords extracted by shuffle from polled words
//    (removes one full agent-atomic round trip vs r6)
//  - depth-2 seq-stamped global ring unchanged (lossless: publish@s+2
//    requires poll@s+1, which requires peers' bar2@s = consumption of s)
//  - "+a" AGPR pins for coord residency (VALU reads AGPRs directly)

#define FPS_B 64
#define FPS_N 65536
#define FPS_M 2048
#define FPS_T 1024
#define FPS_Q 4                    // blocks per batch
#define FPS_GT (FPS_T * FPS_Q)     // 4096 threads per batch
#define FPS_PPT (FPS_N / FPS_GT)   // 16 points per thread
#define FPS_WAVES (FPS_T / 64)     // 16 waves per block

#define SLOT_U64 8                 // 64B global slot
#define BATCH_U64 (FPS_Q * 2 * SLOT_U64)

#define AG_LOAD(p)    __hip_atomic_load((p), __ATOMIC_RELAXED, __HIP_MEMORY_SCOPE_AGENT)
#define AG_STORE(p,v) __hip_atomic_store((p), (v), __ATOMIC_RELAXED, __HIP_MEMORY_SCOPE_AGENT)

// AGPR pin: allocation-only empty asm; keeps coords in the unified file,
// VALU sources AGPRs directly on CDNA4 (no shuttle).
#define PIN4(a,b,c,d) asm volatile("" : "+a"(a), "+a"(b), "+a"(c), "+a"(d))

__global__ __launch_bounds__(FPS_T, 4)
void fps_kernel(const float* __restrict__ x, float* __restrict__ out,
                unsigned long long* __restrict__ cand) {
    const int bid = blockIdx.x;
    // XCD-affine swizzle: batch b's 4 blocks share bid%8 (same XCD under
    // round-robin dispatch). Bijective over [0,256).
    const int c = bid & 7;
    const int v = bid >> 3;
    const int q = v & 3;           // block-in-batch
    const int b = (v >> 2) * 8 + c;

    const float* xb = x + (size_t)b * FPS_N * 3;
    float* ob = out + (size_t)b * FPS_M * 3;
    unsigned long long* cb = cand + (size_t)b * BATCH_U64;

    // plain LDS (no stamps needed: barriers order everything intra-block)
    __shared__ unsigned long long s_entry[FPS_WAVES * 4];  // 16 waves x 4 words
    __shared__ float s_bc[3];

    const int t = threadIdx.x;
    const int wave = t >> 6;
    const int lane = t & 63;
    const int g = q * FPS_T + t;   // 0..4095 within batch

    // one-time coordinate load; point i = k*4096 + g (ascending in k)
    float cx0,cx1,cx2,cx3,cx4,cx5,cx6,cx7,cx8,cx9,cx10,cx11,cx12,cx13,cx14,cx15;
    float cy0,cy1,cy2,cy3,cy4,cy5,cy6,cy7,cy8,cy9,cy10,cy11,cy12,cy13,cy14,cy15;
    float cz0,cz1,cz2,cz3,cz4,cz5,cz6,cz7,cz8,cz9,cz10,cz11,cz12,cz13,cz14,cz15;
    float mind[FPS_PPT];
#define LOADK(k) do { const int i = (k) * FPS_GT + g; \
        cx##k = xb[3*i+0]; cy##k = xb[3*i+1]; cz##k = xb[3*i+2]; \
        mind[k] = INFINITY; } while (0)
    LOADK(0); LOADK(1); LOADK(2); LOADK(3); LOADK(4); LOADK(5); LOADK(6); LOADK(7);
    LOADK(8); LOADK(9); LOADK(10); LOADK(11); LOADK(12); LOADK(13); LOADK(14); LOADK(15);
#undef LOADK

    float px = xb[0], py = xb[1], pz = xb[2];
    if (q == 0 && t == 0) { ob[0] = px; ob[1] = py; ob[2] = pz; }

    long long budget = 1LL << 22;  // fail-safe for the global poll only

    for (int s = 1; s < FPS_M; ++s) {
        // keep the 48 coord values resident across iterations
        PIN4(cx0,cx1,cx2,cx3);   PIN4(cx4,cx5,cx6,cx7);
        PIN4(cx8,cx9,cx10,cx11); PIN4(cx12,cx13,cx14,cx15);
        PIN4(cy0,cy1,cy2,cy3);   PIN4(cy4,cy5,cy6,cy7);
        PIN4(cy8,cy9,cy10,cy11); PIN4(cy12,cy13,cy14,cy15);
        PIN4(cz0,cz1,cz2,cz3);   PIN4(cz4,cz5,cz6,cz7);
        PIN4(cz8,cz9,cz10,cz11); PIN4(cz12,cz13,cz14,cz15);

        float best = -INFINITY;
        int besti = 0;
        float bx = 0.f, by = 0.f, bz = 0.f;
#define STEPK(k) do { \
        const float dx = __fsub_rn(cx##k, px); \
        const float dy = __fsub_rn(cy##k, py); \
        const float dz = __fsub_rn(cz##k, pz); \
        const float sxy = __fadd_rn(__fmul_rn(dx, dx), __fmul_rn(dy, dy)); \
        const float d = __builtin_fmaf(dz, dz, sxy); \
        const float md = fminf(mind[k], d); \
        mind[k] = md; \
        if (md > best) { best = md; besti = (k) * FPS_GT + g; \
                         bx = cx##k; by = cy##k; bz = cz##k; } } while (0)
        STEPK(0); STEPK(1); STEPK(2); STEPK(3); STEPK(4); STEPK(5); STEPK(6); STEPK(7);
        STEPK(8); STEPK(9); STEPK(10); STEPK(11); STEPK(12); STEPK(13); STEPK(14); STEPK(15);
#undef STEPK

        // wave argmax on (val, idx), smallest-index tie-break
#pragma unroll
        for (int m = 32; m >= 1; m >>= 1) {
            const float ov = __shfl_xor(best, m);
            const int   oi = __shfl_xor(besti, m);
            if (ov > best || (ov == best && oi < besti)) { best = ov; besti = oi; }
        }
        // winner lane = besti & 63 (i = k*4096 + q*1024 + t; 4096,1024 ≡ 0 mod 64)
        const int wl = besti & 63;
        const float wx = __shfl(bx, wl);
        const float wy = __shfl(by, wl);
        const float wz = __shfl(bz, wl);

        // wave leaders deposit 4 plain words (low 11 bits left zero for seq)
        if (lane < 4) {
            unsigned long long w;
            if (lane == 0)
                w = ((unsigned long long)__float_as_uint(best) << 32) |
                    ((unsigned long long)((~(unsigned)besti) & 0xFFFFu) << 11);
            else if (lane == 1) w = ((unsigned long long)__float_as_uint(wx) << 32);
            else if (lane == 2) w = ((unsigned long long)__float_as_uint(wy) << 32);
            else                w = ((unsigned long long)__float_as_uint(wz) << 32);
            s_entry[wave * 4 + lane] = w;
        }
        __syncthreads();           // barrier 1: entries visible

        const unsigned long long want = (unsigned long long)s;
        const int ring = s & 1;
        float npx, npy, npz;

        if (wave == 0) {
            // single conflict-free load: lane L holds word (L&3) of wave (L>>2)
            unsigned long long ew = s_entry[lane];
            // butterfly max over the (lane&3)-coset; word-0 coset = block argmax
            unsigned long long u = ((lane & 3) == 0) ? ew : 0ull;
#pragma unroll
            for (int m = 4; m <= 32; m <<= 1) {
                const unsigned long long o = __shfl_xor(u, m);
                if (o > u) u = o;
            }
            const unsigned long long bw = __shfl(u, 0);   // block winner word0
            const int widx = (int)((~(unsigned)(bw >> 11)) & 0xFFFFu);
            const int wv = (widx & 1023) >> 6;            // winner wave in block
            // publish: lanes 0-3 send word0 / x / y / z, seq-stamped
            if (lane < 4) {
                const unsigned long long pw =
                    ((lane == 0) ? bw : s_entry[wv * 4 + lane]) | want;
                AG_STORE(&cb[(q * 2 + ring) * SLOT_U64 + lane], pw);
            }
            // merged poll: lane -> word (lane&15)&3 of slot (lane&15)>>2
            const int gl = lane & 15;
            unsigned long long pv = 0;
            bool ok = false;
            do {
                if (!ok) {
                    pv = AG_LOAD(&cb[((gl >> 2) * 2 + ring) * SLOT_U64 + (gl & 3)]);
                    ok = ((pv & 0x7FFull) == want);
                }
            } while (!__all(ok) && --budget > 0);
            // winner among 4 slots (word0s live in lanes 0,4,8,12)
            const unsigned long long m0 = __shfl(pv, 0);
            const unsigned long long m1 = __shfl(pv, 4);
            const unsigned long long m2 = __shfl(pv, 8);
            const unsigned long long m3 = __shfl(pv, 12);
            const unsigned long long w01 = m0 > m1 ? m0 : m1;
            const unsigned long long w23 = m2 > m3 ? m2 : m3;
            const unsigned long long w = w01 > w23 ? w01 : w23;
            const int wb = (w == m0) ? 0 : ((w == m1) ? 1 : ((w == m2) ? 2 : 3));
            npx = __uint_as_float((unsigned)(__shfl(pv, wb * 4 + 1) >> 32));
            npy = __uint_as_float((unsigned)(__shfl(pv, wb * 4 + 2) >> 32));
            npz = __uint_as_float((unsigned)(__shfl(pv, wb * 4 + 3) >> 32));
            if (lane == 0) { s_bc[0] = npx; s_bc[1] = npy; s_bc[2] = npz; }
            if (q == 0 && lane == 0) {
                ob[3 * s + 0] = npx; ob[3 * s + 1] = npy; ob[3 * s + 2] = npz;
            }
        }
        __syncthreads();           // barrier 2: broadcast visible
        if (wave != 0) { npx = s_bc[0]; npy = s_bc[1]; npz = s_bc[2]; }
        px = npx; py = npy; pz = npz;
    }
}

extern "C" void kernel_launch(void* const* d_in, const int* in_sizes, int n_in,
                              void* d_out, int out_size, void* d_ws, size_t ws_size,
                              hipStream_t stream) {
    const float* x = (const float*)d_in[0];
    float* out = (float*)d_out;
    unsigned long long* cand = (unsigned long long*)d_ws;
    (void)in_sizes; (void)n_in; (void)out_size; (void)ws_size;
    // zero sync workspace each launch (stale stamps can't match: seq >= 1)
    hipMemsetAsync(d_ws, 0, FPS_B * BATCH_U64 * sizeof(unsigned long long), stream);
    fps_kernel<<<FPS_B * FPS_Q, FPS_T, 0, stream>>>(x, out, cand);
}